// Round 6
// baseline (850.375 us; speedup 1.0000x reference)
//
#include <hip/hip_runtime.h>
#include <stdint.h>

#define AS1 __attribute__((address_space(1)))
#define AS3 __attribute__((address_space(3)))

typedef unsigned short US;
typedef __bf16 bf16x8 __attribute__((ext_vector_type(8)));
typedef float f32x4 __attribute__((ext_vector_type(4)));

static constexpr int Bsz = 16384;
static constexpr int DIN = 512;
static constexpr int DH  = 1024;
static constexpr int LDA = 1536;   // Ab row: [h(1024) | x(512)]
static constexpr int LDW = 1536;   // packed weight row: [Wh(1024) | Wx(512)]

__device__ __forceinline__ US f2bf(float f) {
  unsigned u = __float_as_uint(f);
  u += 0x7fffu + ((u >> 16) & 1u);          // RNE
  return (US)(u >> 16);
}
__device__ __forceinline__ float bf2f(US u) { return __uint_as_float(((unsigned)u) << 16); }
__device__ __forceinline__ float sigm(float x) { return 1.f / (1.f + __expf(-x)); }
__device__ __forceinline__ float tanh_f(float x) { return 1.f - 2.f / (1.f + __expf(2.f * x)); }

// ---------- convert kernels ----------
__global__ void pack_A(const float* __restrict__ h, const float* __restrict__ x,
                       US* __restrict__ Ab) {
  const int total = Bsz * 384;              // 1536 cols / 4 per item
  for (int idx = blockIdx.x * blockDim.x + threadIdx.x; idx < total;
       idx += gridDim.x * blockDim.x) {
    int row = idx / 384;
    int c = (idx - row * 384) * 4;
    const float* src = (c < DH) ? (h + (size_t)row * DH + c)
                                : (x + (size_t)row * DIN + (c - DH));
    float4 v = *(const float4*)src;
    ushort4 o;
    o.x = f2bf(v.x); o.y = f2bf(v.y); o.z = f2bf(v.z); o.w = f2bf(v.w);
    *(ushort4*)(Ab + (size_t)row * LDA + c) = o;
  }
}

// pack weight pair [Wh(1024-wide) | Wx(512-wide)] -> dst [1024][1536] bf16
struct PairJob { const float* hW; const float* xW; US* dst; };
struct PairBatch { PairJob j[5]; };
__global__ void conv_pair(PairBatch b) {
  PairJob jb = b.j[blockIdx.y];   // block-uniform — SGPR-resolved
  const int total = DH * 384;     // 1024 rows x 384 float4-items
  for (int idx = blockIdx.x * blockDim.x + threadIdx.x; idx < total;
       idx += gridDim.x * blockDim.x) {
    int r = idx / 384;
    int c = (idx - r * 384) * 4;
    const float* src = (c < DH) ? (jb.hW + (size_t)r * DH + c)
                                : (jb.xW + (size_t)r * DIN + (c - DH));
    float4 v = *(const float4*)src;
    ushort4 o;
    o.x = f2bf(v.x); o.y = f2bf(v.y); o.z = f2bf(v.z); o.w = f2bf(v.w);
    *(ushort4*)(jb.dst + (size_t)r * LDW + c) = o;
  }
}

__global__ void conv_plain(const float* __restrict__ src, US* __restrict__ dst, int n4) {
  for (int i = blockIdx.x * blockDim.x + threadIdx.x; i < n4;
       i += gridDim.x * blockDim.x) {
    float4 v = *(const float4*)(src + (size_t)i * 4);
    ushort4 o;
    o.x = f2bf(v.x); o.y = f2bf(v.y); o.z = f2bf(v.z); o.w = f2bf(v.w);
    *(ushort4*)(dst + (size_t)i * 4) = o;
  }
}

// ---------- segmented-K GEMM, C = A @ W^T, 128x64 tile, fused epilogue ----------
// Compile-time segment counts (R2: runtime-indexed locals -> scratch spill).
// Alias-free dataflow (R3). XCD-aware swizzle (R4: FETCH 398->147 MB).
// R6: 128x64 tile (LDS 24KB, acc 4x2) -> 5-6 resident blocks/CU vs 3-4 (latency-bound fix).
// EPI 0: fused s/r/z by n-range (N=3072).  EPI 3: htilde.  EPI 4: T + final combine.
template <int EPI, int KT0, int KT1, int NX>
__global__ __launch_bounds__(256, 6) void gemm_ep(
    const US* __restrict__ A0, int lda0,
    const US* __restrict__ A1, int lda1,
    const US* __restrict__ W0, int ldw0,
    const US* __restrict__ W1, int ldw1,
    const float* __restrict__ b0, const float* __restrict__ b1,
    const float* __restrict__ b2,
    const void* aux0, const void* aux1, const void* aux2,
    void* out0, void* out1, void* out2) {
  __shared__ __align__(16) US As[128 * 64];
  __shared__ __align__(16) US Bs[64 * 64];

  const int tid  = threadIdx.x;
  const int lane = tid & 63;
  const int w    = tid >> 6;

  // XCD-aware swizzle: p%8 = XCD; each XCD owns a contiguous 16-m-block slab;
  // n varies fastest within a slab so A row-blocks stay in one XCD's L2.
  const int p = blockIdx.x + (int)(gridDim.x * blockIdx.y);
  const int c = p & 7;
  const int q = p >> 3;
  const int nIdx = q % NX;
  const int mIdx = c * 16 + q / NX;       // gridDim.y == 128
  const int mBase = mIdx * 128;
  const int nBase = nIdx * 64;

  f32x4 acc[4][2];
#pragma unroll
  for (int i = 0; i < 4; i++)
#pragma unroll
    for (int j = 0; j < 2; j++) acc[i][j] = f32x4{0.f, 0.f, 0.f, 0.f};

  // XOR swizzle: LDS(m, cc) holds global(m, cc ^ (m&7)) -> 0 bank conflicts
  // (verified R2/R4/R5) while global staging stays coalesced.
  const int rowA = w * 32 + (lane >> 3);          // A staging row (4 rounds of 8)
  const int rowB = w * 16 + (lane >> 3);          // B staging row (2 rounds of 8)
  const int scc  = (lane & 7) ^ ((lane >> 3) & 7);
  const int gOff = scc * 8;
  const int wm = (w & 1) * 64, wn = (w >> 1) * 32;
  const int quad = lane >> 4, l15 = lane & 15;
  const int sw = l15 & 7;

#define K_TILE_LOOP(Ap, lda, Wp, ldw, KT)                                          \
  {                                                                                \
    const US* ga = (Ap) + (size_t)(mBase + rowA) * (lda) + gOff;                   \
    const US* gw = (Wp) + (size_t)(nBase + rowB) * (ldw) + gOff;                   \
    const size_t a8 = (size_t)8 * (lda), w8 = (size_t)8 * (ldw);                   \
    for (int k = 0; k < (KT); ++k) {                                               \
      _Pragma("unroll")                                                            \
      for (int i = 0; i < 4; i++)                                                  \
        __builtin_amdgcn_global_load_lds((AS1 const void*)(ga + i * a8),           \
            (AS3 void*)&As[(w * 32 + i * 8) * 64], 16, 0, 0);                      \
      _Pragma("unroll")                                                            \
      for (int i = 0; i < 2; i++)                                                  \
        __builtin_amdgcn_global_load_lds((AS1 const void*)(gw + i * w8),           \
            (AS3 void*)&Bs[(w * 16 + i * 8) * 64], 16, 0, 0);                      \
      __builtin_amdgcn_s_waitcnt(0x0f70);                                          \
      __syncthreads();                                                             \
      _Pragma("unroll")                                                            \
      for (int ks = 0; ks < 2; ++ks) {                                             \
        bf16x8 af[4], bw[2];                                                       \
        _Pragma("unroll")                                                          \
        for (int i = 0; i < 4; i++)                                                \
          af[i] = *(const bf16x8*)&As[(wm + i * 16 + l15) * 64 +                   \
                                      (((ks * 4 + quad) ^ sw) * 8)];               \
        _Pragma("unroll")                                                          \
        for (int j = 0; j < 2; j++)                                                \
          bw[j] = *(const bf16x8*)&Bs[(wn + j * 16 + l15) * 64 +                   \
                                      (((ks * 4 + quad) ^ sw) * 8)];               \
        _Pragma("unroll")                                                          \
        for (int i = 0; i < 4; i++)                                                \
          _Pragma("unroll")                                                        \
          for (int j = 0; j < 2; j++)                                              \
            acc[i][j] = __builtin_amdgcn_mfma_f32_16x16x32_bf16(af[i], bw[j],      \
                                                                acc[i][j], 0, 0, 0);\
      }                                                                            \
      __syncthreads();                                                             \
      ga += 64; gw += 64;                                                          \
    }                                                                              \
  }

  if constexpr (KT0 > 0) K_TILE_LOOP(A0, lda0, W0, ldw0, KT0);
  if constexpr (KT1 > 0) K_TILE_LOOP(A1, lda1, W1, ldw1, KT1);
#undef K_TILE_LOOP

  // epilogue: row = mBase+wm+i*16+quad*4+r ; col = nBase+wn+j*16+l15
#pragma unroll
  for (int i = 0; i < 4; i++) {
#pragma unroll
    for (int j = 0; j < 2; j++) {
      const int col = nBase + wn + j * 16 + l15;
#pragma unroll
      for (int r = 0; r < 4; r++) {
        const int row = mBase + wm + i * 16 + quad * 4 + r;
        float v = acc[i][j][r];
        if constexpr (EPI == 0) {
          // fused s/r/z: gate is block-uniform (64-col tile within 1024 boundary)
          const int gate = nBase >> 10;
          const int cl = col & 1023;
          if (gate == 0) {
            const float* delta = (const float*)aux0;
            const float* wst   = (const float*)aux1;
            v += b0[cl] + delta[row] * wst[cl];
            ((US*)out0)[(size_t)row * DH + cl] = f2bf(tanh_f(v));
          } else if (gate == 1) {
            const float* hp = (const float*)aux2;   // pristine f32 h_prev
            v += b1[cl];
            float rr = sigm(v);
            ((US*)out1)[(size_t)row * DH + cl] =
                f2bf(rr * hp[(size_t)row * DH + cl]);
          } else {
            v += b2[cl];
            ((US*)out2)[(size_t)row * DH + cl] = f2bf(sigm(v));
          }
        } else if constexpr (EPI == 3) {
          v += b0[col];
          ((US*)out0)[(size_t)row * DH + col] = f2bf(tanh_f(v));
        } else {
          const float* hp = (const float*)aux0;   // pristine f32 h_prev
          const US* Zp = (const US*)aux1;
          const US* Hp = (const US*)aux2;
          v += b0[col];
          float T = sigm(v);
          size_t o = (size_t)row * DH + col;
          float z = bf2f(Zp[o]), ht = bf2f(Hp[o]);
          float h = hp[o];
          ((float*)out0)[o] = (1.f - z) * (T * h) + z * ht;
        }
      }
    }
  }
}

extern "C" void kernel_launch(void* const* d_in, const int* in_sizes, int n_in,
                              void* d_out, int out_size, void* d_ws, size_t ws_size,
                              hipStream_t stream) {
  const float* x_t   = (const float*)d_in[0];
  const float* delta = (const float*)d_in[1];
  const float* h_prev= (const float*)d_in[2];
  const float* W_sh  = (const float*)d_in[3];
  const float* W_sx  = (const float*)d_in[4];
  const float* W_st  = (const float*)d_in[5];
  const float* b_s   = (const float*)d_in[6];
  const float* WTh   = (const float*)d_in[7];
  const float* WTx   = (const float*)d_in[8];
  const float* WTs   = (const float*)d_in[9];
  const float* b_T   = (const float*)d_in[10];
  const float* W_rh  = (const float*)d_in[11];
  const float* W_rx  = (const float*)d_in[12];
  const float* b_r   = (const float*)d_in[13];
  const float* W_zh  = (const float*)d_in[14];
  const float* W_zx  = (const float*)d_in[15];
  const float* b_z   = (const float*)d_in[16];
  const float* W_h   = (const float*)d_in[17];
  const float* W_x   = (const float*)d_in[18];
  const float* b_    = (const float*)d_in[19];
  float* out = (float*)d_out;

  char* ws = (char*)d_ws;
  US* Ab  = (US*)ws;                        size_t off = (size_t)Bsz * LDA * 2;
  US* Sb  = (US*)(ws + off);                off += (size_t)Bsz * DH * 2;
  US* RH  = (US*)(ws + off);                off += (size_t)Bsz * DH * 2;
  US* Zb  = (US*)(ws + off);                off += (size_t)Bsz * DH * 2;
  US* HTb = (US*)(ws + off);                off += (size_t)Bsz * DH * 2;
  const size_t WPACK = (size_t)DH * LDW * 2;         // 1024 x 1536 bf16
  US* bWsrz = (US*)(ws + off); off += 3 * WPACK;     // [s|r|z] packed rows
  US* bWhx  = (US*)(ws + off); off += WPACK;
  US* bWThx = (US*)(ws + off); off += WPACK;
  US* bWTs  = (US*)(ws + off); off += (size_t)DH * DH * 2;

  // Stage 0: convert/pack
  pack_A<<<dim3(8192), 256, 0, stream>>>(h_prev, x_t, Ab);
  PairBatch pb;
  pb.j[0] = {W_sh, W_sx, bWsrz};
  pb.j[1] = {W_rh, W_rx, bWsrz + (size_t)DH * LDW};
  pb.j[2] = {W_zh, W_zx, bWsrz + (size_t)2 * DH * LDW};
  pb.j[3] = {W_h,  W_x,  bWhx};
  pb.j[4] = {WTh,  WTx,  bWThx};
  conv_pair<<<dim3(512, 5), 256, 0, stream>>>(pb);
  conv_plain<<<dim3(512), 256, 0, stream>>>(WTs, bWTs, DH * DH / 4);

  const US* A_x = Ab + DH;     // x segment (K=512) inside Ab

  // Phase 1: fused s,r,z — one N=3072 GEMM, single K-segment (packed W)
  gemm_ep<0, 24, 0, 48><<<dim3(48, 128), 256, 0, stream>>>(
      Ab, LDA, nullptr, 0,
      bWsrz, LDW, nullptr, 0,
      b_s, b_r, b_z,
      delta, W_st, h_prev,
      (void*)Sb, (void*)RH, (void*)Zb);

  // Phase 2: h_tilde = tanh([rh] @ Wh^T + [x] @ Wx^T + b)
  gemm_ep<3, 16, 8, 16><<<dim3(16, 128), 256, 0, stream>>>(
      RH, DH, A_x, LDA,
      bWhx, LDW, bWhx + DH, LDW,
      b_, nullptr, nullptr,
      nullptr, nullptr, nullptr,
      (void*)HTb, nullptr, nullptr);

  // Phase 3: T gate + final combine -> d_out (f32)
  gemm_ep<4, 24, 16, 16><<<dim3(16, 128), 256, 0, stream>>>(
      Ab, LDA, Sb, DH,
      bWThx, LDW, bWTs, DH,
      b_T, nullptr, nullptr,
      h_prev, Zb, HTb,
      (void*)out, nullptr, nullptr);
}